// Round 5
// baseline (377.169 us; speedup 1.0000x reference)
//
#include <hip/hip_runtime.h>
#include <cmath>
#include <stdint.h>

#define B_    8
#define NIN_  256
#define D_    128
#define K_    1024
#define N_    4096
#define P_    (B_ * N_)          // 32768 positions
#define MARGIN_ 2e-4f

typedef __attribute__((ext_vector_type(8))) short bf16x8;   // 8 bf16 (4 VGPRs)
typedef __attribute__((ext_vector_type(4))) float f32x4;    // 4 fp32 acc

// ---- workspace layout (bytes), ~66 MB ----
#define WS_ZSUM   0                           // K*D*4 = 524288   (zeroed)
#define WS_CNT    524288                      // 4096             (zeroed)
#define WS_FLAGC  528384                      // 4096             (zeroed)
#define WS_MEMSET 532480
#define WS_OFF    532480                      // 4096
#define WS_QSQ    536576                      // 4096
#define WS_QNORM  540672                      // 4096
#define WS_KSTAR  544768                      // P*4
#define WS_RANK   675840                      // P*4
#define WS_PLIST  806912                      // P*4
#define WS_KLIST  937984                      // P*4
#define WS_FLIST  1069056                     // P*4
#define WS_WT     1200128                     // NIN*D*4
#define WS_ZPM    1331200                     // P*D*4 = 16 MiB (p-major fp32 ze)
#define WS_ZESQ   (WS_ZPM + 16777216)
#define WS_ZEN    (WS_ZESQ + 131072)
#define WS_ZE2F   (WS_ZEN + 131072)           // 2048 pt x 12 c x 64 lane x 16B = 24 MiB
#define WS_EMB2F  (WS_ZE2F + 25165824)        // 64 kt x 12 x 64 x 16B = 768 KiB
#define WS_VAL1   (WS_EMB2F + 786432)         // 64*P*4 = 8 MiB
#define WS_IDX1   (WS_VAL1 + 8388608)
#define WS_VAL2   (WS_IDX1 + 8388608)

__device__ inline unsigned short f2bf(float v) {          // RTNE fp32->bf16
  union { float f; uint32_t u; } c; c.f = v;
  return (unsigned short)((c.u + 0x7FFFu + ((c.u >> 16) & 1u)) >> 16);
}
__device__ inline float bf2f(unsigned short b) {
  union { float f; uint32_t u; } c; c.u = ((uint32_t)b) << 16; return c.f;
}

// ---- prep: Wt transpose, q_sq/q_norm, emb2f MFMA B-fragments ----
// emb2f frag (kt,c,lane): 8 bf16, element j = B'[k=kt*16+(lane&15)]
// [kk=c*32+(lane>>4)*8+j] with B' = [emb_hi | emb_lo | emb_hi] (seg = kk>>7).
__global__ __launch_bounds__(256) void prep_kernel(
    const float* __restrict__ W, const float* __restrict__ emb,
    float* __restrict__ Wt, float* __restrict__ q_sq, float* __restrict__ q_norm,
    uint4* __restrict__ emb2f)
{
  const int tid = threadIdx.x;
  const int bid = blockIdx.x;
  if (bid < 128) {
    int t = bid * 256 + tid;
    int c = t >> 7, d = t & 127;
    Wt[t] = W[d * NIN_ + c];
  } else if (bid < 132) {
    int k = (bid - 128) * 256 + tid;      // 0..1023
    const float* e = emb + (size_t)k * D_;
    float s = 0.f;
    #pragma unroll 8
    for (int d = 0; d < D_; ++d) s = fmaf(e[d], e[d], s);
    q_sq[k] = s;
    q_norm[k] = sqrtf(s);
  } else {
    const int kt = bid - 132;             // 0..63
    #pragma unroll
    for (int i = 0; i < 3; ++i) {
      int fi = tid * 3 + i;               // 0..767
      int c  = fi >> 6;
      int fl = fi & 63;
      int k  = kt * 16 + (fl & 15);
      int q  = fl >> 4;
      unsigned short h[8];
      #pragma unroll
      for (int j = 0; j < 8; ++j) {
        int kk = c * 32 + q * 8 + j;
        int seg = kk >> 7;
        int d = kk & 127;
        float v = emb[(size_t)k * D_ + d];
        unsigned short hb = f2bf(v);
        if (seg == 1) hb = f2bf(v - bf2f(hb));   // lo segment
        h[j] = hb;
      }
      uint4 u;
      u.x = h[0] | ((uint32_t)h[1] << 16);
      u.y = h[2] | ((uint32_t)h[3] << 16);
      u.z = h[4] | ((uint32_t)h[5] << 16);
      u.w = h[6] | ((uint32_t)h[7] << 16);
      emb2f[(size_t)kt * 768 + c * 64 + fl] = u;
    }
  }
}

// ---- ze = W @ z: p-major fp32 + ze_sq/ze_norm + ze2f A-fragments ----
// A' = [ze_hi | ze_hi | ze_lo] (seg = kk>>7; lo at seg==2).
__global__ __launch_bounds__(512) void ze_kernel(
    const float* __restrict__ z, const float* __restrict__ Wt,
    float* __restrict__ ze_pm, float* __restrict__ ze_sq,
    float* __restrict__ ze_norm, uint4* __restrict__ ze2f)
{
  __shared__ float tile[64][132];     // +4 pad
  __shared__ float sqpart[8][64];
  const int t    = threadIdx.x;
  const int lane = t & 63;
  const int wv   = __builtin_amdgcn_readfirstlane(t >> 6);   // 0..7
  const int p    = blockIdx.x * 64 + lane;
  const int b    = p >> 12;
  const int n    = p & (N_ - 1);

  float acc[16];
  #pragma unroll
  for (int j = 0; j < 16; ++j) acc[j] = 0.f;
  const float* zp = z + (size_t)b * NIN_ * N_ + n;
  const float* wp = Wt + wv * 16;
  #pragma unroll 4
  for (int c = 0; c < NIN_; ++c) {
    float zv = zp[(size_t)c * N_];                 // coalesced v-load
    #pragma unroll
    for (int j = 0; j < 16; ++j)
      acc[j] = fmaf(wp[c * D_ + j], zv, acc[j]);   // wave-uniform -> s_load
  }
  #pragma unroll
  for (int j = 0; j < 16; ++j) tile[lane][wv * 16 + j] = acc[j];
  float s = 0.f;
  #pragma unroll
  for (int j = 0; j < 16; ++j) s = fmaf(acc[j], acc[j], s);
  sqpart[wv][lane] = s;
  __syncthreads();
  if (wv == 0) {                        // same order as round 4 (passed)
    float tt = sqpart[0][lane];
    #pragma unroll
    for (int w = 1; w < 8; ++w) tt += sqpart[w][lane];
    ze_sq[p] = tt;
    ze_norm[p] = sqrtf(tt);
  }
  // p-major fp32 store via LDS transpose
  const int row = t >> 5;               // 0..15
  const int c4  = (t & 31) * 4;         // 0..124
  #pragma unroll
  for (int r = 0; r < 4; ++r) {
    int pr = r * 16 + row;
    float4 v = *(const float4*)&tile[pr][c4];
    *(float4*)&ze_pm[(size_t)(blockIdx.x * 64 + pr) * D_ + c4] = v;
  }
  // ze2f A-fragments: 4 pos-tiles x 768 frags, 6 per thread
  #pragma unroll
  for (int i = 0; i < 6; ++i) {
    int fi  = t * 6 + i;                // 0..3071
    int lpt = fi / 768;
    int r2  = fi - lpt * 768;
    int c   = r2 >> 6;
    int fl  = r2 & 63;
    int pl  = lpt * 16 + (fl & 15);
    int q   = fl >> 4;
    unsigned short h[8];
    #pragma unroll
    for (int j = 0; j < 8; ++j) {
      int kk = c * 32 + q * 8 + j;
      int seg = kk >> 7;
      int d = kk & 127;
      float v = tile[pl][d];
      unsigned short hb = f2bf(v);
      if (seg == 2) hb = f2bf(v - bf2f(hb));     // lo segment
      h[j] = hb;
    }
    uint4 u;
    u.x = h[0] | ((uint32_t)h[1] << 16);
    u.y = h[2] | ((uint32_t)h[3] << 16);
    u.z = h[4] | ((uint32_t)h[5] << 16);
    u.w = h[6] | ((uint32_t)h[7] << 16);
    int ptg = blockIdx.x * 4 + lpt;
    ze2f[(size_t)ptg * 768 + c * 64 + fl] = u;
  }
}

// ---- MFMA distance + per-16-code (min1,k1,min2) partials ----
// grid = 8 kb x 64 pb. Block 8 waves; wave w: codes g*16..g*16+15 (g=kb*8+w),
// emb frags VGPR-resident. 32 pos-tiles streamed via double-buffered LDS.
// C layout: row=(lane>>4)*4+reg = position, col=lane&15 = code [m89/m91].
__global__ __launch_bounds__(512, 4) void mfma_argmin_kernel(
    const uint4* __restrict__ ze2f, const uint4* __restrict__ emb2f,
    const float* __restrict__ ze_sq, const float* __restrict__ ze_norm,
    const float* __restrict__ q_sq, const float* __restrict__ q_norm,
    float* __restrict__ val1, int* __restrict__ idx1, float* __restrict__ val2)
{
  __shared__ uint4 abuf[2][768];        // 2 x 12KB pos-tile fragments
  const int tid  = threadIdx.x;
  const int lane = tid & 63;
  const int w    = __builtin_amdgcn_readfirstlane(tid >> 6);
  const int kb   = blockIdx.x & 7;
  const int pb   = blockIdx.x >> 3;
  const int g    = kb * 8 + w;          // partial index, code-ascending
  const int code = g * 16 + (lane & 15);
  const int q    = lane >> 4;

  uint4 bfr[12];                        // resident B-frags (48 VGPRs)
  #pragma unroll
  for (int c = 0; c < 12; ++c)
    bfr[c] = emb2f[(size_t)g * 768 + c * 64 + lane];
  const float qsq_l = q_sq[code];
  const float qn_l  = q_norm[code];

  const int pt0 = pb * 32;
  uint4 s0, s1;
  {
    const uint4* src = ze2f + (size_t)pt0 * 768;
    s0 = src[tid];
    if (tid < 256) s1 = src[512 + tid];
  }
  for (int t = 0; t < 32; ++t) {
    const int buf = t & 1;
    abuf[buf][tid] = s0;                      // stage tile t (vmcnt wait here,
    if (tid < 256) abuf[buf][512 + tid] = s1; //  latency hidden by prev compute)
    __syncthreads();
    if (t + 1 < 32) {                         // prefetch t+1 AFTER barrier
      const uint4* src = ze2f + (size_t)(pt0 + t + 1) * 768;
      s0 = src[tid];
      if (tid < 256) s1 = src[512 + tid];
    }
    const int ptg = pt0 + t;
    f32x4 acc = {0.f, 0.f, 0.f, 0.f};
    #pragma unroll
    for (int c = 0; c < 12; ++c) {
      bf16x8 af = *reinterpret_cast<const bf16x8*>(&abuf[buf][c * 64 + lane]);
      union { uint4 u; bf16x8 h; } bu; bu.u = bfr[c];
      acc = __builtin_amdgcn_mfma_f32_16x16x32_bf16(af, bu.h, acc, 0, 0, 0);
    }
    f32x4 zsq4 = *(const f32x4*)&ze_sq[ptg * 16 + q * 4];
    f32x4 zn4  = *(const f32x4*)&ze_norm[ptg * 16 + q * 4];
    float m1[4], m2[4]; int k1[4];
    #pragma unroll
    for (int r = 0; r < 4; ++r) {
      float dsq = fmaxf(zsq4[r] + qsq_l - 2.0f * acc[r], 0.0f);
      m1[r] = sqrtf(dsq) / (zn4[r] + qn_l);   // approx snorm (screening only)
      k1[r] = code;
      m2[r] = 1e30f;
    }
    #pragma unroll
    for (int m = 1; m <= 8; m <<= 1) {        // 16-lane argmin butterfly
      #pragma unroll
      for (int r = 0; r < 4; ++r) {
        float om1 = __shfl_xor(m1[r], m);
        int   ok1 = __shfl_xor(k1[r], m);
        float om2 = __shfl_xor(m2[r], m);
        bool take = (om1 < m1[r]) || (om1 == m1[r] && ok1 < k1[r]);
        float loser = take ? m1[r] : om1;
        if (take) { m1[r] = om1; k1[r] = ok1; }
        m2[r] = fminf(fminf(m2[r], om2), loser);
      }
    }
    if ((lane & 15) == 0) {
      const size_t o = (size_t)g * P_ + ptg * 16 + q * 4;
      *(float4*)&val1[o] = make_float4(m1[0], m1[1], m1[2], m1[3]);
      *(int4*)&idx1[o]   = make_int4(k1[0], k1[1], k1[2], k1[3]);
      *(float4*)&val2[o] = make_float4(m2[0], m2[1], m2[2], m2[3]);
    }
  }
}

// ---- resolve 64 partials -> kstar + flag list for fp32 fallback ----
__global__ __launch_bounds__(256) void resolve_kernel(
    const float* __restrict__ val1, const int* __restrict__ idx1,
    const float* __restrict__ val2, int* __restrict__ kstar,
    int* __restrict__ flaglist, int* __restrict__ flagcnt)
{
  const int p = blockIdx.x * 256 + threadIdx.x;
  float m1 = 1e30f, m2 = 1e30f; int k1 = 0;
  for (int g = 0; g < 64; ++g) {        // g ascending == codes ascending
    float v1 = val1[(size_t)g * P_ + p];
    int   i1 = idx1[(size_t)g * P_ + p];
    float v2 = val2[(size_t)g * P_ + p];
    bool take = v1 < m1;                // strict < keeps lowest-k on ties
    float loser = take ? m1 : v1;
    if (take) { m1 = v1; k1 = i1; }
    m2 = fminf(fminf(m2, v2), loser);
  }
  kstar[p] = k1;
  if (m2 - m1 <= MARGIN_) {             // ambiguous under approx error
    int s = atomicAdd(flagcnt, 1);
    flaglist[s] = p;
  }
}

// ---- exact fp32 rescan for flagged positions (matches round-4 op order) ----
__global__ __launch_bounds__(256) void fallback_kernel(
    const float* __restrict__ ze_pm, const float* __restrict__ emb,
    const float* __restrict__ ze_sq, const float* __restrict__ ze_norm,
    const float* __restrict__ q_sq, const float* __restrict__ q_norm,
    const int* __restrict__ flaglist, const int* __restrict__ flagcnt,
    int* __restrict__ kstar)
{
  const int lane = threadIdx.x & 63;
  const int wid  = blockIdx.x * 4 + (threadIdx.x >> 6);
  const int cnt  = *flagcnt;
  for (int i = wid; i < cnt; i += 1024) {
    const int p = flaglist[i];
    const float* zrow = ze_pm + (size_t)p * D_;   // uniform -> broadcast
    const float zsq = ze_sq[p], zn = ze_norm[p];
    float bs = 1e30f; int bk = 0;
    for (int tt = 0; tt < 16; ++tt) {
      const int k = tt * 64 + lane;               // ascending per lane
      const float* e = emb + (size_t)k * D_;
      float dot = 0.f;
      #pragma unroll 8
      for (int d = 0; d < D_; ++d) dot = fmaf(zrow[d], e[d], dot);
      float dsq = fmaxf(fmaf(-2.0f, dot, zsq + q_sq[k]), 0.0f);
      float sn = sqrtf(dsq) / (zn + q_norm[k]);
      if (sn < bs) { bs = sn; bk = k; }
    }
    #pragma unroll
    for (int m = 1; m <= 32; m <<= 1) {           // 64-lane, lower-k ties
      float ov = __shfl_xor(bs, m);
      int   ok = __shfl_xor(bk, m);
      if (ov < bs || (ov == bs && ok < bk)) { bs = ov; bk = ok; }
    }
    if (lane == 0) kstar[p] = bk;
  }
}

__global__ __launch_bounds__(256) void rank_kernel(
    const int* __restrict__ kstar, int* __restrict__ rank, int* __restrict__ counts)
{
  const int p = blockIdx.x * 256 + threadIdx.x;
  rank[p] = atomicAdd(&counts[kstar[p]], 1);
}

__global__ __launch_bounds__(1024) void prefix_kernel(
    const int* __restrict__ counts, const float* __restrict__ ema_denom,
    int* __restrict__ offsets, float* __restrict__ out_den)
{
  __shared__ int s[1024];
  const int t = threadIdx.x;
  const int c = counts[t];
  s[t] = c;
  __syncthreads();
  for (int off = 1; off < 1024; off <<= 1) {
    int v = (t >= off) ? s[t - off] : 0;
    __syncthreads();
    s[t] += v;
    __syncthreads();
  }
  offsets[t] = s[t] - c;
  out_den[t] = 0.99f * ema_denom[t] + 0.01f * (float)c;
}

__global__ __launch_bounds__(256) void scatter_kernel(
    const int* __restrict__ kstar, const int* __restrict__ rank,
    const int* __restrict__ offsets, int* __restrict__ pos_list,
    int* __restrict__ k_list)
{
  const int p = blockIdx.x * 256 + threadIdx.x;
  const int k = kstar[p];
  const int slot = offsets[k] + rank[p];
  pos_list[slot] = p;
  k_list[slot] = k;
}

// ---- zq straight-through write (reads p-major ze; L1 reuse across j) ----
__global__ __launch_bounds__(512) void zq_kernel(
    const float* __restrict__ ze_pm, const float* __restrict__ emb,
    const int* __restrict__ kstar, float* __restrict__ out)
{
  const int tid = threadIdx.x;
  const int lane = tid & 63;
  const int w = __builtin_amdgcn_readfirstlane(tid >> 6);
  const int p = blockIdx.x * 64 + lane;
  const int b = p >> 12;
  const int n = p & (N_ - 1);
  const int kst = kstar[p];
  const float* zr = ze_pm + (size_t)p * D_ + w * 16;
  const float* ek = emb + (size_t)kst * D_ + w * 16;
  float* op = out + (size_t)b * D_ * N_ + (size_t)(w * 16) * N_ + n;
  #pragma unroll
  for (int j = 0; j < 16; ++j) {
    float zev = zr[j];
    float qv = ek[j];
    op[(size_t)j * N_] = zev + (qv - zev);   // ref rounding order
  }
}

// ---- segment-sum over code-sorted positions ----
__global__ __launch_bounds__(128) void gsum_kernel(
    const float* __restrict__ ze_pm, const int* __restrict__ pos_list,
    const int* __restrict__ k_list, float* __restrict__ z_sum)
{
  const int d  = threadIdx.x;
  const int i0 = blockIdx.x * 32;
  int   kprev = -1;
  float acc = 0.f;
  #pragma unroll
  for (int ii = 0; ii < 32; ++ii) {
    int p = pos_list[i0 + ii];
    int k = k_list[i0 + ii];
    if (k != kprev) {
      if (kprev >= 0) atomicAdd(&z_sum[(size_t)kprev * D_ + d], acc);
      acc = 0.f;
      kprev = k;
    }
    acc += ze_pm[(size_t)p * D_ + d];
  }
  if (kprev >= 0) atomicAdd(&z_sum[(size_t)kprev * D_ + d], acc);
}

__global__ __launch_bounds__(256) void finalize_num_kernel(
    const float* __restrict__ ema_numer, const float* __restrict__ z_sum,
    float* __restrict__ out)
{
  const int t = blockIdx.x * 256 + threadIdx.x;
  float* out_num = out + (size_t)B_ * D_ * N_;
  out_num[t] = 0.99f * ema_numer[t] + 0.01f * z_sum[t];
}

extern "C" void kernel_launch(void* const* d_in, const int* in_sizes, int n_in,
                              void* d_out, int out_size, void* d_ws, size_t ws_size,
                              hipStream_t stream)
{
  (void)in_sizes; (void)n_in; (void)out_size; (void)ws_size;
  const float* z         = (const float*)d_in[0];
  const float* W         = (const float*)d_in[1];
  const float* emb       = (const float*)d_in[2];
  const float* ema_numer = (const float*)d_in[3];
  const float* ema_denom = (const float*)d_in[4];
  float* out = (float*)d_out;
  char*  ws  = (char*)d_ws;
  float* z_sum   = (float*)(ws + WS_ZSUM);
  int*   counts  = (int*)(ws + WS_CNT);
  int*   flagcnt = (int*)(ws + WS_FLAGC);
  int*   offsets = (int*)(ws + WS_OFF);
  float* q_sq    = (float*)(ws + WS_QSQ);
  float* q_norm  = (float*)(ws + WS_QNORM);
  int*   kstar   = (int*)(ws + WS_KSTAR);
  int*   rank    = (int*)(ws + WS_RANK);
  int*   plist   = (int*)(ws + WS_PLIST);
  int*   klist   = (int*)(ws + WS_KLIST);
  int*   flist   = (int*)(ws + WS_FLIST);
  float* Wt      = (float*)(ws + WS_WT);
  float* ze_pm   = (float*)(ws + WS_ZPM);
  float* ze_sq   = (float*)(ws + WS_ZESQ);
  float* ze_norm = (float*)(ws + WS_ZEN);
  uint4* ze2f    = (uint4*)(ws + WS_ZE2F);
  uint4* emb2f   = (uint4*)(ws + WS_EMB2F);
  float* val1    = (float*)(ws + WS_VAL1);
  int*   idx1    = (int*)(ws + WS_IDX1);
  float* val2    = (float*)(ws + WS_VAL2);
  float* out_den = out + (size_t)B_ * D_ * N_ + K_ * D_;

  hipMemsetAsync(ws, 0, WS_MEMSET, stream);   // z_sum + counts + flagcnt

  prep_kernel<<<196, 256, 0, stream>>>(W, emb, Wt, q_sq, q_norm, emb2f);
  ze_kernel<<<P_ / 64, 512, 0, stream>>>(z, Wt, ze_pm, ze_sq, ze_norm, ze2f);
  mfma_argmin_kernel<<<512, 512, 0, stream>>>(ze2f, emb2f, ze_sq, ze_norm,
                                              q_sq, q_norm, val1, idx1, val2);
  resolve_kernel<<<P_ / 256, 256, 0, stream>>>(val1, idx1, val2, kstar,
                                               flist, flagcnt);
  fallback_kernel<<<256, 256, 0, stream>>>(ze_pm, emb, ze_sq, ze_norm,
                                           q_sq, q_norm, flist, flagcnt, kstar);
  rank_kernel<<<P_ / 256, 256, 0, stream>>>(kstar, rank, counts);
  prefix_kernel<<<1, 1024, 0, stream>>>(counts, ema_denom, offsets, out_den);
  scatter_kernel<<<P_ / 256, 256, 0, stream>>>(kstar, rank, offsets, plist, klist);
  zq_kernel<<<P_ / 64, 512, 0, stream>>>(ze_pm, emb, kstar, out);
  gsum_kernel<<<P_ / 32, 128, 0, stream>>>(ze_pm, plist, klist, z_sum);
  finalize_num_kernel<<<K_ * D_ / 256, 256, 0, stream>>>(ema_numer, z_sum, out);
}

// Round 6
// 319.668 us; speedup vs baseline: 1.1799x; 1.1799x over previous
//
#include <hip/hip_runtime.h>
#include <cmath>
#include <stdint.h>

#define B_    8
#define NIN_  256
#define D_    128
#define K_    1024
#define N_    4096
#define P_    (B_ * N_)          // 32768 positions
#define MARGIN_M 1e-4f           // screening margin in m = dsq/den^2 domain

typedef __attribute__((ext_vector_type(8))) short bf16x8;   // 8 bf16 (4 VGPRs)
typedef __attribute__((ext_vector_type(4))) float f32x4;    // 4 fp32 acc

// ---- workspace layout (bytes), ~51 MB ----
#define WS_ZSUM   0                 // K*D*4 = 524288 (zeroed)
#define WS_CNT    524288            // 4096           (zeroed)
#define WS_FLAGC  528384            // 4096           (zeroed)
#define WS_MEMSET 532480
#define WS_OFF    532480
#define WS_QSQ    536576
#define WS_QNORM  540672
#define WS_KSTAR  544768            // P*4
#define WS_RANK   675840
#define WS_PLIST  806912
#define WS_KLIST  937984
#define WS_FLIST  1069056
#define WS_WT     1200128           // NIN*D*4
#define WS_ZPM    1331200           // P*D*4 = 16 MiB (p-major fp32 ze)
#define WS_ZESQ   18108416          // P*4
#define WS_ZEN    18239488          // P*4
#define WS_ZE2F   18370560          // 2048 pt x 12 c x 64 lane x 16B = 24 MiB
#define WS_EMB2F  43536384          // 64 kt x 12 x 64 x 16B = 768 KiB
#define WS_VAL1   44322816          // 16*P*4 = 2 MiB
#define WS_IDX1   46419968          // 2 MiB
#define WS_VAL2   48517120          // 2 MiB

__device__ inline unsigned short f2bf(float v) {          // RTNE fp32->bf16
  union { float f; uint32_t u; } c; c.f = v;
  return (unsigned short)((c.u + 0x7FFFu + ((c.u >> 16) & 1u)) >> 16);
}
__device__ inline float bf2f(unsigned short b) {
  union { float f; uint32_t u; } c; c.u = ((uint32_t)b) << 16; return c.f;
}
__device__ inline uint32_t pack2(float a, float b, int lo) {
  unsigned short ha = f2bf(a); if (lo) ha = f2bf(a - bf2f(ha));
  unsigned short hb = f2bf(b); if (lo) hb = f2bf(b - bf2f(hb));
  return (uint32_t)ha | ((uint32_t)hb << 16);
}

// ---- prep: Wt transpose, q_sq/q_norm, emb2f B-fragments ----
// Fragment (kt,c,lane): code k = kt*16+(lane&15), elements kk = c*32+(lane>>4)*8+j
// B' = [emb_hi | emb_lo | emb_hi], seg = kk>>7 (frag-uniform; 8 contiguous d's).
__global__ __launch_bounds__(256) void prep_kernel(
    const float* __restrict__ W, const float* __restrict__ emb,
    float* __restrict__ Wt, float* __restrict__ q_sq, float* __restrict__ q_norm,
    uint4* __restrict__ emb2f)
{
  const int tid = threadIdx.x;
  const int bid = blockIdx.x;
  if (bid < 128) {
    int t = bid * 256 + tid;
    int c = t >> 7, d = t & 127;
    Wt[t] = W[d * NIN_ + c];
  } else if (bid < 132) {
    int k = (bid - 128) * 256 + tid;
    const float* e = emb + (size_t)k * D_;
    float s = 0.f;
    #pragma unroll 8
    for (int d = 0; d < D_; ++d) s = fmaf(e[d], e[d], s);
    q_sq[k] = s;
    q_norm[k] = sqrtf(s);
  } else {
    const int kt = bid - 132;             // 0..63
    #pragma unroll
    for (int i = 0; i < 3; ++i) {
      int f    = i * 256 + tid;           // 0..767
      int c    = f >> 6;
      int lane = f & 63;
      int k    = kt * 16 + (lane & 15);
      int q    = lane >> 4;
      int kk0  = c * 32 + q * 8;
      int lo   = (kk0 >> 7) == 1;
      int d0   = kk0 & 127;
      float4 v0 = *(const float4*)&emb[(size_t)k * D_ + d0];
      float4 v1 = *(const float4*)&emb[(size_t)k * D_ + d0 + 4];
      uint4 u;
      u.x = pack2(v0.x, v0.y, lo);
      u.y = pack2(v0.z, v0.w, lo);
      u.z = pack2(v1.x, v1.y, lo);
      u.w = pack2(v1.z, v1.w, lo);
      emb2f[(size_t)kt * 768 + f] = u;
    }
  }
}

// ---- ze = W @ z: p-major fp32, ze_sq/ze_norm, ze2f A-fragments ----
// A' = [ze_hi | ze_hi | ze_lo] (seg==2 -> lo).
__global__ __launch_bounds__(512) void ze_kernel(
    const float* __restrict__ z, const float* __restrict__ Wt,
    float* __restrict__ ze_pm, float* __restrict__ ze_sq,
    float* __restrict__ ze_norm, uint4* __restrict__ ze2f)
{
  __shared__ float tile[64][132];     // +4 pad
  __shared__ float sqpart[8][64];
  const int t    = threadIdx.x;
  const int lane = t & 63;
  const int wv   = __builtin_amdgcn_readfirstlane(t >> 6);   // 0..7
  const int p    = blockIdx.x * 64 + lane;
  const int b    = p >> 12;
  const int n    = p & (N_ - 1);

  float acc[16];
  #pragma unroll
  for (int j = 0; j < 16; ++j) acc[j] = 0.f;
  const float* zp = z + (size_t)b * NIN_ * N_ + n;
  const float* wp = Wt + wv * 16;
  #pragma unroll 4
  for (int c = 0; c < NIN_; ++c) {
    float zv = zp[(size_t)c * N_];                 // coalesced v-load
    #pragma unroll
    for (int j = 0; j < 16; ++j)
      acc[j] = fmaf(wp[c * D_ + j], zv, acc[j]);   // wave-uniform -> s_load
  }
  #pragma unroll
  for (int j = 0; j < 16; ++j) tile[lane][wv * 16 + j] = acc[j];
  float s = 0.f;
  #pragma unroll
  for (int j = 0; j < 16; ++j) s = fmaf(acc[j], acc[j], s);
  sqpart[wv][lane] = s;
  __syncthreads();
  if (wv == 0) {                        // same sum order as round 4 (passed)
    float tt = sqpart[0][lane];
    #pragma unroll
    for (int w = 1; w < 8; ++w) tt += sqpart[w][lane];
    ze_sq[p] = tt;
    ze_norm[p] = sqrtf(tt);
  }
  // p-major fp32 store via LDS transpose
  const int row = t >> 5;               // 0..15
  const int c4  = (t & 31) * 4;         // 0..124
  #pragma unroll
  for (int r = 0; r < 4; ++r) {
    int pr = r * 16 + row;
    float4 v = *(const float4*)&tile[pr][c4];
    *(float4*)&ze_pm[(size_t)(blockIdx.x * 64 + pr) * D_ + c4] = v;
  }
  // ze2f A-fragments: 4 pos-tiles x 768 frags = 3072, 6/thread, vectorized
  #pragma unroll
  for (int i = 0; i < 6; ++i) {
    int f    = i * 512 + t;             // 0..3071
    int lane_f = f & 63;
    int g    = f >> 6;                  // 0..47 = lpt*12 + c
    int c    = g % 12;
    int lpt  = g / 12;
    int pl   = lpt * 16 + (lane_f & 15);
    int q    = lane_f >> 4;
    int kk0  = c * 32 + q * 8;
    int lo   = (kk0 >> 7) == 2;
    int d0   = kk0 & 127;
    float4 v0 = *(const float4*)&tile[pl][d0];
    float4 v1 = *(const float4*)&tile[pl][d0 + 4];
    uint4 u;
    u.x = pack2(v0.x, v0.y, lo);
    u.y = pack2(v0.z, v0.w, lo);
    u.z = pack2(v1.x, v1.y, lo);
    u.w = pack2(v1.z, v1.w, lo);
    ze2f[((size_t)(blockIdx.x * 4 + lpt) * 12 + c) * 64 + lane_f] = u;
  }
}

// ---- MFMA GEMM-argmin, m97-shaped: block = 128 pos x 256 codes, 8 waves,
// wave tile = 4x4 16x16 subtiles (8 ds_read_b128 : 16 MFMA per K-step).
// Screening value m = dsq*rcp(den)^2 (monotone w/ snorm); running (m1,k1,m2)
// in regs; one 16-lane butterfly per position at the end. ----
__global__ __launch_bounds__(512, 2) void mfma_argmin_kernel(
    const uint4* __restrict__ ze2f, const uint4* __restrict__ emb2f,
    const float* __restrict__ ze_sq, const float* __restrict__ ze_norm,
    const float* __restrict__ q_sq, const float* __restrict__ q_norm,
    float* __restrict__ val1, int* __restrict__ idx1, float* __restrict__ val2)
{
  __shared__ uint4 As[2][512];          // 8 pos-subtiles x 64 lanes
  __shared__ uint4 Bs[2][1024];         // 16 code-subtiles x 64 lanes
  const int tid  = threadIdx.x;
  const int lane = tid & 63;
  const int tw   = tid >> 6;            // 0..7
  const int kb   = blockIdx.x & 3;      // code strip (256 codes)
  const int pb   = blockIdx.x >> 2;     // pos strip (128 positions)
  const int wm   = tw & 1;              // pos half
  const int wn   = tw >> 1;             // code quarter

  const uint4* a_base  = ze2f + ((size_t)(pb * 8 + tw) * 12) * 64 + lane;
  const uint4* b_base0 = emb2f + ((size_t)(kb * 16 + tw) * 12) * 64 + lane;
  const uint4* b_base1 = emb2f + ((size_t)(kb * 16 + tw + 8) * 12) * 64 + lane;

  f32x4 acc[4][4];
  #pragma unroll
  for (int i = 0; i < 4; ++i)
    #pragma unroll
    for (int j = 0; j < 4; ++j) acc[i][j] = (f32x4){0.f, 0.f, 0.f, 0.f};

  uint4 pa = a_base[0], pb0 = b_base0[0], pb1 = b_base1[0];
  for (int c = 0; c < 12; ++c) {
    const int buf = c & 1;
    As[buf][tid] = pa;
    Bs[buf][tid] = pb0;
    Bs[buf][512 + tid] = pb1;
    __syncthreads();
    if (c + 1 < 12) {
      pa  = a_base[(c + 1) * 64];
      pb0 = b_base0[(c + 1) * 64];
      pb1 = b_base1[(c + 1) * 64];
    }
    uint4 afr[4], bfr[4];
    #pragma unroll
    for (int i = 0; i < 4; ++i) afr[i] = As[buf][(wm * 4 + i) * 64 + lane];
    #pragma unroll
    for (int j = 0; j < 4; ++j) bfr[j] = Bs[buf][(wn * 4 + j) * 64 + lane];
    #pragma unroll
    for (int i = 0; i < 4; ++i) {
      union { uint4 u; bf16x8 h; } au; au.u = afr[i];
      #pragma unroll
      for (int j = 0; j < 4; ++j) {
        union { uint4 u; bf16x8 h; } bu; bu.u = bfr[j];
        acc[i][j] = __builtin_amdgcn_mfma_f32_16x16x32_bf16(au.h, bu.h,
                                                            acc[i][j], 0, 0, 0);
      }
    }
  }

  // ---- epilogue ----
  const int col = lane & 15;
  const int q   = lane >> 4;
  float qsq_l[4], qn_l[4]; int kg[4];
  #pragma unroll
  for (int j = 0; j < 4; ++j) {
    kg[j]    = kb * 256 + wn * 64 + j * 16 + col;    // ascending in j
    qsq_l[j] = q_sq[kg[j]];
    qn_l[j]  = q_norm[kg[j]];
  }
  const int g = kb * 4 + wn;            // partial idx; g ascending == k ascending
  #pragma unroll
  for (int i = 0; i < 4; ++i) {
    const int pbase = pb * 128 + wm * 64 + i * 16 + q * 4;
    f32x4 zs = *(const f32x4*)&ze_sq[pbase];
    f32x4 zn = *(const f32x4*)&ze_norm[pbase];
    float m1r[4], m2r[4]; int k1r[4];
    #pragma unroll
    for (int r = 0; r < 4; ++r) { m1r[r] = 1e30f; m2r[r] = 1e30f; k1r[r] = 0; }
    #pragma unroll
    for (int j = 0; j < 4; ++j) {
      #pragma unroll
      for (int r = 0; r < 4; ++r) {
        float dsq = fmaxf(zs[r] + qsq_l[j] - 2.0f * acc[i][j][r], 0.0f);
        float den = zn[r] + qn_l[j];
        float rd  = __builtin_amdgcn_rcpf(den);
        float m   = dsq * rd * rd;
        bool take = m < m1r[r];                  // strict < keeps lowest k
        float loser = take ? m1r[r] : m;
        if (take) { m1r[r] = m; k1r[r] = kg[j]; }
        m2r[r] = fminf(m2r[r], loser);
      }
    }
    #pragma unroll
    for (int ms = 1; ms <= 8; ms <<= 1) {        // 16-lane argmin butterfly
      #pragma unroll
      for (int r = 0; r < 4; ++r) {
        float om1 = __shfl_xor(m1r[r], ms);
        int   ok1 = __shfl_xor(k1r[r], ms);
        float om2 = __shfl_xor(m2r[r], ms);
        bool take = (om1 < m1r[r]) || (om1 == m1r[r] && ok1 < k1r[r]);
        float loser = take ? m1r[r] : om1;
        if (take) { m1r[r] = om1; k1r[r] = ok1; }
        m2r[r] = fminf(fminf(m2r[r], om2), loser);
      }
    }
    if (col == 0) {
      const size_t o = (size_t)g * P_ + pbase;
      *(float4*)&val1[o] = make_float4(m1r[0], m1r[1], m1r[2], m1r[3]);
      *(int4*)&idx1[o]   = make_int4(k1r[0], k1r[1], k1r[2], k1r[3]);
      *(float4*)&val2[o] = make_float4(m2r[0], m2r[1], m2r[2], m2r[3]);
    }
  }
}

// ---- resolve 16 partials -> kstar + flagged ambiguous positions ----
__global__ __launch_bounds__(256) void resolve_kernel(
    const float* __restrict__ val1, const int* __restrict__ idx1,
    const float* __restrict__ val2, int* __restrict__ kstar,
    int* __restrict__ flaglist, int* __restrict__ flagcnt)
{
  const int p = blockIdx.x * 256 + threadIdx.x;
  float m1 = 1e30f, m2 = 1e30f; int k1 = 0;
  #pragma unroll
  for (int g = 0; g < 16; ++g) {        // g ascending == codes ascending
    float v1 = val1[(size_t)g * P_ + p];
    int   i1 = idx1[(size_t)g * P_ + p];
    float v2 = val2[(size_t)g * P_ + p];
    bool take = v1 < m1;
    float loser = take ? m1 : v1;
    if (take) { m1 = v1; k1 = i1; }
    m2 = fminf(fminf(m2, v2), loser);
  }
  kstar[p] = k1;
  if (m2 - m1 <= MARGIN_M) {
    int s = atomicAdd(flagcnt, 1);
    flaglist[s] = p;
  }
}

// ---- exact fp32 rescan for flagged positions (round-4 op order, passed) ----
__global__ __launch_bounds__(256) void fallback_kernel(
    const float* __restrict__ ze_pm, const float* __restrict__ emb,
    const float* __restrict__ ze_sq, const float* __restrict__ ze_norm,
    const float* __restrict__ q_sq, const float* __restrict__ q_norm,
    const int* __restrict__ flaglist, const int* __restrict__ flagcnt,
    int* __restrict__ kstar)
{
  const int lane = threadIdx.x & 63;
  const int wid  = blockIdx.x * 4 + (threadIdx.x >> 6);
  const int cnt  = *flagcnt;
  for (int i = wid; i < cnt; i += 1024) {
    const int p = flaglist[i];
    const float* zrow = ze_pm + (size_t)p * D_;
    const float zsq = ze_sq[p], zn = ze_norm[p];
    float bs = 1e30f; int bk = 0;
    for (int tt = 0; tt < 16; ++tt) {
      const int k = tt * 64 + lane;
      const float* e = emb + (size_t)k * D_;
      float dot = 0.f;
      #pragma unroll 8
      for (int d = 0; d < D_; ++d) dot = fmaf(zrow[d], e[d], dot);
      float dsq = fmaxf(fmaf(-2.0f, dot, zsq + q_sq[k]), 0.0f);
      float sn = sqrtf(dsq) / (zn + q_norm[k]);
      if (sn < bs) { bs = sn; bk = k; }
    }
    #pragma unroll
    for (int m = 1; m <= 32; m <<= 1) {
      float ov = __shfl_xor(bs, m);
      int   ok = __shfl_xor(bk, m);
      if (ov < bs || (ov == bs && ok < bk)) { bs = ov; bk = ok; }
    }
    if (lane == 0) kstar[p] = bk;
  }
}

__global__ __launch_bounds__(256) void rank_kernel(
    const int* __restrict__ kstar, int* __restrict__ rank, int* __restrict__ counts)
{
  const int p = blockIdx.x * 256 + threadIdx.x;
  rank[p] = atomicAdd(&counts[kstar[p]], 1);
}

__global__ __launch_bounds__(1024) void prefix_kernel(
    const int* __restrict__ counts, const float* __restrict__ ema_denom,
    int* __restrict__ offsets, float* __restrict__ out_den)
{
  __shared__ int s[1024];
  const int t = threadIdx.x;
  const int c = counts[t];
  s[t] = c;
  __syncthreads();
  for (int off = 1; off < 1024; off <<= 1) {
    int v = (t >= off) ? s[t - off] : 0;
    __syncthreads();
    s[t] += v;
    __syncthreads();
  }
  offsets[t] = s[t] - c;
  out_den[t] = 0.99f * ema_denom[t] + 0.01f * (float)c;
}

__global__ __launch_bounds__(256) void scatter_kernel(
    const int* __restrict__ kstar, const int* __restrict__ rank,
    const int* __restrict__ offsets, int* __restrict__ pos_list,
    int* __restrict__ k_list)
{
  const int p = blockIdx.x * 256 + threadIdx.x;
  const int k = kstar[p];
  const int slot = offsets[k] + rank[p];
  pos_list[slot] = p;
  k_list[slot] = k;
}

__global__ __launch_bounds__(512) void zq_kernel(
    const float* __restrict__ ze_pm, const float* __restrict__ emb,
    const int* __restrict__ kstar, float* __restrict__ out)
{
  const int tid = threadIdx.x;
  const int lane = tid & 63;
  const int w = __builtin_amdgcn_readfirstlane(tid >> 6);
  const int p = blockIdx.x * 64 + lane;
  const int b = p >> 12;
  const int n = p & (N_ - 1);
  const int kst = kstar[p];
  const float* zr = ze_pm + (size_t)p * D_ + w * 16;
  const float* ek = emb + (size_t)kst * D_ + w * 16;
  float* op = out + (size_t)b * D_ * N_ + (size_t)(w * 16) * N_ + n;
  #pragma unroll
  for (int j = 0; j < 16; ++j) {
    float zev = zr[j];
    float qv = ek[j];
    op[(size_t)j * N_] = zev + (qv - zev);   // ref rounding order
  }
}

__global__ __launch_bounds__(128) void gsum_kernel(
    const float* __restrict__ ze_pm, const int* __restrict__ pos_list,
    const int* __restrict__ k_list, float* __restrict__ z_sum)
{
  const int d  = threadIdx.x;
  const int i0 = blockIdx.x * 32;
  int   kprev = -1;
  float acc = 0.f;
  #pragma unroll
  for (int ii = 0; ii < 32; ++ii) {
    int p = pos_list[i0 + ii];
    int k = k_list[i0 + ii];
    if (k != kprev) {
      if (kprev >= 0) atomicAdd(&z_sum[(size_t)kprev * D_ + d], acc);
      acc = 0.f;
      kprev = k;
    }
    acc += ze_pm[(size_t)p * D_ + d];
  }
  if (kprev >= 0) atomicAdd(&z_sum[(size_t)kprev * D_ + d], acc);
}

__global__ __launch_bounds__(256) void finalize_num_kernel(
    const float* __restrict__ ema_numer, const float* __restrict__ z_sum,
    float* __restrict__ out)
{
  const int t = blockIdx.x * 256 + threadIdx.x;
  float* out_num = out + (size_t)B_ * D_ * N_;
  out_num[t] = 0.99f * ema_numer[t] + 0.01f * z_sum[t];
}

extern "C" void kernel_launch(void* const* d_in, const int* in_sizes, int n_in,
                              void* d_out, int out_size, void* d_ws, size_t ws_size,
                              hipStream_t stream)
{
  (void)in_sizes; (void)n_in; (void)out_size; (void)ws_size;
  const float* z         = (const float*)d_in[0];
  const float* W         = (const float*)d_in[1];
  const float* emb       = (const float*)d_in[2];
  const float* ema_numer = (const float*)d_in[3];
  const float* ema_denom = (const float*)d_in[4];
  float* out = (float*)d_out;
  char*  ws  = (char*)d_ws;
  float* z_sum   = (float*)(ws + WS_ZSUM);
  int*   counts  = (int*)(ws + WS_CNT);
  int*   flagcnt = (int*)(ws + WS_FLAGC);
  int*   offsets = (int*)(ws + WS_OFF);
  float* q_sq    = (float*)(ws + WS_QSQ);
  float* q_norm  = (float*)(ws + WS_QNORM);
  int*   kstar   = (int*)(ws + WS_KSTAR);
  int*   rank    = (int*)(ws + WS_RANK);
  int*   plist   = (int*)(ws + WS_PLIST);
  int*   klist   = (int*)(ws + WS_KLIST);
  int*   flist   = (int*)(ws + WS_FLIST);
  float* Wt      = (float*)(ws + WS_WT);
  float* ze_pm   = (float*)(ws + WS_ZPM);
  float* ze_sq   = (float*)(ws + WS_ZESQ);
  float* ze_norm = (float*)(ws + WS_ZEN);
  uint4* ze2f    = (uint4*)(ws + WS_ZE2F);
  uint4* emb2f   = (uint4*)(ws + WS_EMB2F);
  float* val1    = (float*)(ws + WS_VAL1);
  int*   idx1    = (int*)(ws + WS_IDX1);
  float* val2    = (float*)(ws + WS_VAL2);
  float* out_den = out + (size_t)B_ * D_ * N_ + K_ * D_;

  hipMemsetAsync(ws, 0, WS_MEMSET, stream);   // z_sum + counts + flagcnt

  prep_kernel<<<196, 256, 0, stream>>>(W, emb, Wt, q_sq, q_norm, emb2f);
  ze_kernel<<<P_ / 64, 512, 0, stream>>>(z, Wt, ze_pm, ze_sq, ze_norm, ze2f);
  mfma_argmin_kernel<<<1024, 512, 0, stream>>>(ze2f, emb2f, ze_sq, ze_norm,
                                               q_sq, q_norm, val1, idx1, val2);
  resolve_kernel<<<P_ / 256, 256, 0, stream>>>(val1, idx1, val2, kstar,
                                               flist, flagcnt);
  fallback_kernel<<<256, 256, 0, stream>>>(ze_pm, emb, ze_sq, ze_norm,
                                           q_sq, q_norm, flist, flagcnt, kstar);
  rank_kernel<<<P_ / 256, 256, 0, stream>>>(kstar, rank, counts);
  prefix_kernel<<<1, 1024, 0, stream>>>(counts, ema_denom, offsets, out_den);
  scatter_kernel<<<P_ / 256, 256, 0, stream>>>(kstar, rank, offsets, plist, klist);
  zq_kernel<<<P_ / 64, 512, 0, stream>>>(ze_pm, emb, kstar, out);
  gsum_kernel<<<P_ / 32, 128, 0, stream>>>(ze_pm, plist, klist, z_sum);
  finalize_num_kernel<<<K_ * D_ / 256, 256, 0, stream>>>(ema_numer, z_sum, out);
}

// Round 7
// 261.151 us; speedup vs baseline: 1.4443x; 1.2241x over previous
//
#include <hip/hip_runtime.h>
#include <cmath>
#include <stdint.h>

#define B_    8
#define NIN_  256
#define D_    128
#define K_    1024
#define N_    4096
#define P_    (B_ * N_)          // 32768 positions
#define MARGIN_M 1e-4f           // screening margin in m = dsq/den^2 domain

typedef __attribute__((ext_vector_type(8))) short bf16x8;   // 8 bf16 (4 VGPRs)
typedef __attribute__((ext_vector_type(4))) float f32x4;    // 4 fp32 acc

// ---- workspace layout (bytes), ~51 MB ----
#define WS_ZSUM   0                 // K*D*4 = 524288 (zeroed)
#define WS_CNT    524288            // 4096           (zeroed)
#define WS_FLAGC  528384            // 4096           (zeroed)
#define WS_MEMSET 532480
#define WS_OFF    532480
#define WS_QSQ    536576
#define WS_QNORM  540672
#define WS_KSTAR  544768            // P*4
#define WS_RANK   675840
#define WS_PLIST  806912
#define WS_KLIST  937984
#define WS_FLIST  1069056
#define WS_WT     1200128           // NIN*D*4
#define WS_ZPM    1331200           // P*D*4 = 16 MiB (p-major fp32 ze)
#define WS_ZESQ   18108416          // P*4
#define WS_ZEN    18239488          // P*4
#define WS_ZE2F   18370560          // 2048 pt x 12 c x 64 lane x 16B = 24 MiB
#define WS_EMB2F  43536384          // 64 kt x 12 x 64 x 16B = 768 KiB
#define WS_VAL1   44322816          // 16*P*4 = 2 MiB
#define WS_IDX1   46419968          // 2 MiB
#define WS_VAL2   48517120          // 2 MiB

__device__ inline unsigned short f2bf(float v) {          // RTNE fp32->bf16
  union { float f; uint32_t u; } c; c.f = v;
  return (unsigned short)((c.u + 0x7FFFu + ((c.u >> 16) & 1u)) >> 16);
}
__device__ inline float bf2f(unsigned short b) {
  union { float f; uint32_t u; } c; c.u = ((uint32_t)b) << 16; return c.f;
}
__device__ inline uint32_t pack2(float a, float b, int lo) {
  unsigned short ha = f2bf(a); if (lo) ha = f2bf(a - bf2f(ha));
  unsigned short hb = f2bf(b); if (lo) hb = f2bf(b - bf2f(hb));
  return (uint32_t)ha | ((uint32_t)hb << 16);
}

// ---- prep: Wt transpose, q_sq/q_norm, emb2f B-fragments ----
__global__ __launch_bounds__(256) void prep_kernel(
    const float* __restrict__ W, const float* __restrict__ emb,
    float* __restrict__ Wt, float* __restrict__ q_sq, float* __restrict__ q_norm,
    uint4* __restrict__ emb2f)
{
  const int tid = threadIdx.x;
  const int bid = blockIdx.x;
  if (bid < 128) {
    int t = bid * 256 + tid;
    int c = t >> 7, d = t & 127;
    Wt[t] = W[d * NIN_ + c];
  } else if (bid < 132) {
    int k = (bid - 128) * 256 + tid;
    const float* e = emb + (size_t)k * D_;
    float s = 0.f;
    #pragma unroll 8
    for (int d = 0; d < D_; ++d) s = fmaf(e[d], e[d], s);
    q_sq[k] = s;
    q_norm[k] = sqrtf(s);
  } else {
    const int kt = bid - 132;             // 0..63
    #pragma unroll
    for (int i = 0; i < 3; ++i) {
      int f    = i * 256 + tid;           // 0..767
      int c    = f >> 6;
      int lane = f & 63;
      int k    = kt * 16 + (lane & 15);
      int q    = lane >> 4;
      int kk0  = c * 32 + q * 8;
      int lo   = (kk0 >> 7) == 1;
      int d0   = kk0 & 127;
      float4 v0 = *(const float4*)&emb[(size_t)k * D_ + d0];
      float4 v1 = *(const float4*)&emb[(size_t)k * D_ + d0 + 4];
      uint4 u;
      u.x = pack2(v0.x, v0.y, lo);
      u.y = pack2(v0.z, v0.w, lo);
      u.z = pack2(v1.x, v1.y, lo);
      u.w = pack2(v1.z, v1.w, lo);
      emb2f[(size_t)kt * 768 + f] = u;
    }
  }
}

// ---- ze = W @ z: p-major fp32, ze_sq/ze_norm, ze2f A-fragments ----
__global__ __launch_bounds__(512) void ze_kernel(
    const float* __restrict__ z, const float* __restrict__ Wt,
    float* __restrict__ ze_pm, float* __restrict__ ze_sq,
    float* __restrict__ ze_norm, uint4* __restrict__ ze2f)
{
  __shared__ float tile[64][132];     // +4 pad
  __shared__ float sqpart[8][64];
  const int t    = threadIdx.x;
  const int lane = t & 63;
  const int wv   = __builtin_amdgcn_readfirstlane(t >> 6);   // 0..7
  const int p    = blockIdx.x * 64 + lane;
  const int b    = p >> 12;
  const int n    = p & (N_ - 1);

  float acc[16];
  #pragma unroll
  for (int j = 0; j < 16; ++j) acc[j] = 0.f;
  const float* zp = z + (size_t)b * NIN_ * N_ + n;
  const float* wp = Wt + wv * 16;
  #pragma unroll 4
  for (int c = 0; c < NIN_; ++c) {
    float zv = zp[(size_t)c * N_];                 // coalesced v-load
    #pragma unroll
    for (int j = 0; j < 16; ++j)
      acc[j] = fmaf(wp[c * D_ + j], zv, acc[j]);   // wave-uniform -> s_load
  }
  #pragma unroll
  for (int j = 0; j < 16; ++j) tile[lane][wv * 16 + j] = acc[j];
  float s = 0.f;
  #pragma unroll
  for (int j = 0; j < 16; ++j) s = fmaf(acc[j], acc[j], s);
  sqpart[wv][lane] = s;
  __syncthreads();
  if (wv == 0) {                        // same sum order as round 4 (passed)
    float tt = sqpart[0][lane];
    #pragma unroll
    for (int w = 1; w < 8; ++w) tt += sqpart[w][lane];
    ze_sq[p] = tt;
    ze_norm[p] = sqrtf(tt);
  }
  // p-major fp32 store via LDS transpose
  const int row = t >> 5;               // 0..15
  const int c4  = (t & 31) * 4;         // 0..124
  #pragma unroll
  for (int r = 0; r < 4; ++r) {
    int pr = r * 16 + row;
    float4 v = *(const float4*)&tile[pr][c4];
    *(float4*)&ze_pm[(size_t)(blockIdx.x * 64 + pr) * D_ + c4] = v;
  }
  // ze2f A-fragments: 4 pos-tiles x 768 frags = 3072, 6/thread, vectorized
  #pragma unroll
  for (int i = 0; i < 6; ++i) {
    int f    = i * 512 + t;             // 0..3071
    int lane_f = f & 63;
    int g    = f >> 6;                  // 0..47 = lpt*12 + c
    int c    = g % 12;
    int lpt  = g / 12;
    int pl   = lpt * 16 + (lane_f & 15);
    int q    = lane_f >> 4;
    int kk0  = c * 32 + q * 8;
    int lo   = (kk0 >> 7) == 2;
    int d0   = kk0 & 127;
    float4 v0 = *(const float4*)&tile[pl][d0];
    float4 v1 = *(const float4*)&tile[pl][d0 + 4];
    uint4 u;
    u.x = pack2(v0.x, v0.y, lo);
    u.y = pack2(v0.z, v0.w, lo);
    u.z = pack2(v1.x, v1.y, lo);
    u.w = pack2(v1.z, v1.w, lo);
    ze2f[((size_t)(blockIdx.x * 4 + lpt) * 12 + c) * 64 + lane_f] = u;
  }
}

// ---- MFMA GEMM-argmin, m97-shaped (unchanged from round 6) ----
__global__ __launch_bounds__(512, 2) void mfma_argmin_kernel(
    const uint4* __restrict__ ze2f, const uint4* __restrict__ emb2f,
    const float* __restrict__ ze_sq, const float* __restrict__ ze_norm,
    const float* __restrict__ q_sq, const float* __restrict__ q_norm,
    float* __restrict__ val1, int* __restrict__ idx1, float* __restrict__ val2)
{
  __shared__ uint4 As[2][512];
  __shared__ uint4 Bs[2][1024];
  const int tid  = threadIdx.x;
  const int lane = tid & 63;
  const int tw   = tid >> 6;
  const int kb   = blockIdx.x & 3;
  const int pb   = blockIdx.x >> 2;
  const int wm   = tw & 1;
  const int wn   = tw >> 1;

  const uint4* a_base  = ze2f + ((size_t)(pb * 8 + tw) * 12) * 64 + lane;
  const uint4* b_base0 = emb2f + ((size_t)(kb * 16 + tw) * 12) * 64 + lane;
  const uint4* b_base1 = emb2f + ((size_t)(kb * 16 + tw + 8) * 12) * 64 + lane;

  f32x4 acc[4][4];
  #pragma unroll
  for (int i = 0; i < 4; ++i)
    #pragma unroll
    for (int j = 0; j < 4; ++j) acc[i][j] = (f32x4){0.f, 0.f, 0.f, 0.f};

  uint4 pa = a_base[0], pb0 = b_base0[0], pb1 = b_base1[0];
  for (int c = 0; c < 12; ++c) {
    const int buf = c & 1;
    As[buf][tid] = pa;
    Bs[buf][tid] = pb0;
    Bs[buf][512 + tid] = pb1;
    __syncthreads();
    if (c + 1 < 12) {
      pa  = a_base[(c + 1) * 64];
      pb0 = b_base0[(c + 1) * 64];
      pb1 = b_base1[(c + 1) * 64];
    }
    uint4 afr[4], bfr[4];
    #pragma unroll
    for (int i = 0; i < 4; ++i) afr[i] = As[buf][(wm * 4 + i) * 64 + lane];
    #pragma unroll
    for (int j = 0; j < 4; ++j) bfr[j] = Bs[buf][(wn * 4 + j) * 64 + lane];
    #pragma unroll
    for (int i = 0; i < 4; ++i) {
      union { uint4 u; bf16x8 h; } au; au.u = afr[i];
      #pragma unroll
      for (int j = 0; j < 4; ++j) {
        union { uint4 u; bf16x8 h; } bu; bu.u = bfr[j];
        acc[i][j] = __builtin_amdgcn_mfma_f32_16x16x32_bf16(au.h, bu.h,
                                                            acc[i][j], 0, 0, 0);
      }
    }
  }

  const int col = lane & 15;
  const int q   = lane >> 4;
  float qsq_l[4], qn_l[4]; int kg[4];
  #pragma unroll
  for (int j = 0; j < 4; ++j) {
    kg[j]    = kb * 256 + wn * 64 + j * 16 + col;
    qsq_l[j] = q_sq[kg[j]];
    qn_l[j]  = q_norm[kg[j]];
  }
  const int g = kb * 4 + wn;
  #pragma unroll
  for (int i = 0; i < 4; ++i) {
    const int pbase = pb * 128 + wm * 64 + i * 16 + q * 4;
    f32x4 zs = *(const f32x4*)&ze_sq[pbase];
    f32x4 zn = *(const f32x4*)&ze_norm[pbase];
    float m1r[4], m2r[4]; int k1r[4];
    #pragma unroll
    for (int r = 0; r < 4; ++r) { m1r[r] = 1e30f; m2r[r] = 1e30f; k1r[r] = 0; }
    #pragma unroll
    for (int j = 0; j < 4; ++j) {
      #pragma unroll
      for (int r = 0; r < 4; ++r) {
        float dsq = fmaxf(zs[r] + qsq_l[j] - 2.0f * acc[i][j][r], 0.0f);
        float den = zn[r] + qn_l[j];
        float rd  = __builtin_amdgcn_rcpf(den);
        float m   = dsq * rd * rd;
        bool take = m < m1r[r];
        float loser = take ? m1r[r] : m;
        if (take) { m1r[r] = m; k1r[r] = kg[j]; }
        m2r[r] = fminf(m2r[r], loser);
      }
    }
    #pragma unroll
    for (int ms = 1; ms <= 8; ms <<= 1) {
      #pragma unroll
      for (int r = 0; r < 4; ++r) {
        float om1 = __shfl_xor(m1r[r], ms);
        int   ok1 = __shfl_xor(k1r[r], ms);
        float om2 = __shfl_xor(m2r[r], ms);
        bool take = (om1 < m1r[r]) || (om1 == m1r[r] && ok1 < k1r[r]);
        float loser = take ? m1r[r] : om1;
        if (take) { m1r[r] = om1; k1r[r] = ok1; }
        m2r[r] = fminf(fminf(m2r[r], om2), loser);
      }
    }
    if (col == 0) {
      const size_t o = (size_t)g * P_ + pbase;
      *(float4*)&val1[o] = make_float4(m1r[0], m1r[1], m1r[2], m1r[3]);
      *(int4*)&idx1[o]   = make_int4(k1r[0], k1r[1], k1r[2], k1r[3]);
      *(float4*)&val2[o] = make_float4(m2r[0], m2r[1], m2r[2], m2r[3]);
    }
  }
}

// ---- resolve 16 partials -> kstar; rank unflagged; flag ambiguous ----
__global__ __launch_bounds__(256) void resolve_kernel(
    const float* __restrict__ val1, const int* __restrict__ idx1,
    const float* __restrict__ val2, int* __restrict__ kstar,
    int* __restrict__ rank, int* __restrict__ counts,
    int* __restrict__ flaglist, int* __restrict__ flagcnt)
{
  const int p = blockIdx.x * 256 + threadIdx.x;
  float m1 = 1e30f, m2 = 1e30f; int k1 = 0;
  #pragma unroll
  for (int g = 0; g < 16; ++g) {        // g ascending == codes ascending
    float v1 = val1[(size_t)g * P_ + p];
    int   i1 = idx1[(size_t)g * P_ + p];
    float v2 = val2[(size_t)g * P_ + p];
    bool take = v1 < m1;
    float loser = take ? m1 : v1;
    if (take) { m1 = v1; k1 = i1; }
    m2 = fminf(fminf(m2, v2), loser);
  }
  kstar[p] = k1;
  if (m2 - m1 <= MARGIN_M) {
    int s = atomicAdd(flagcnt, 1);
    flaglist[s] = p;                    // ranked later by fallback
  } else {
    rank[p] = atomicAdd(&counts[k1], 1);
  }
}

// ---- exact fp32 rescan, BLOCK-parallel: 4 waves per flagged position.
// Wave w covers codes [256w,256w+256) in 4 lane-parallel tiles; dot is the
// validated single serial fmaf chain (same rounding as rounds 4-6). ----
__global__ __launch_bounds__(256) void fallback_kernel(
    const float* __restrict__ ze_pm, const float* __restrict__ emb,
    const float* __restrict__ ze_sq, const float* __restrict__ ze_norm,
    const float* __restrict__ q_sq, const float* __restrict__ q_norm,
    const int* __restrict__ flaglist, const int* __restrict__ flagcnt,
    int* __restrict__ kstar, int* __restrict__ rank, int* __restrict__ counts)
{
  __shared__ float zlds[128];
  __shared__ float wbs[4];
  __shared__ int   wbk[4];
  const int tid  = threadIdx.x;
  const int lane = tid & 63;
  const int w    = tid >> 6;            // 0..3
  const int cnt  = *flagcnt;
  for (int i = blockIdx.x; i < cnt; i += gridDim.x) {
    const int p = flaglist[i];
    __syncthreads();                    // protect zlds/wbs reuse
    if (tid < 128) zlds[tid] = ze_pm[(size_t)p * D_ + tid];
    __syncthreads();
    const float zsq = ze_sq[p], zn = ze_norm[p];
    float bs = 1e30f; int bk = 0;
    #pragma unroll
    for (int tt = 0; tt < 4; ++tt) {
      const int k = (w * 4 + tt) * 64 + lane;     // ascending per lane
      const float* e = emb + (size_t)k * D_;
      float dot = 0.f;
      #pragma unroll 8
      for (int d = 0; d < D_; ++d)
        dot = fmaf(zlds[d], e[d], dot);           // LDS broadcast + v-load
      float dsq = fmaxf(fmaf(-2.0f, dot, zsq + q_sq[k]), 0.0f);
      float sn  = sqrtf(dsq) / (zn + q_norm[k]);
      if (sn < bs) { bs = sn; bk = k; }
    }
    #pragma unroll
    for (int m = 1; m <= 32; m <<= 1) {           // 64-lane, lower-k ties
      float ov = __shfl_xor(bs, m);
      int   ok = __shfl_xor(bk, m);
      if (ov < bs || (ov == bs && ok < bk)) { bs = ov; bk = ok; }
    }
    if (lane == 0) { wbs[w] = bs; wbk[w] = bk; }
    __syncthreads();
    if (tid == 0) {
      float fb = wbs[0]; int fk = wbk[0];
      #pragma unroll
      for (int ww = 1; ww < 4; ++ww) {            // ascending k-ranges
        if (wbs[ww] < fb) { fb = wbs[ww]; fk = wbk[ww]; }
      }
      kstar[p] = fk;
      rank[p] = atomicAdd(&counts[fk], 1);
    }
  }
}

__global__ __launch_bounds__(1024) void prefix_kernel(
    const int* __restrict__ counts, const float* __restrict__ ema_denom,
    int* __restrict__ offsets, float* __restrict__ out_den)
{
  __shared__ int s[1024];
  const int t = threadIdx.x;
  const int c = counts[t];
  s[t] = c;
  __syncthreads();
  for (int off = 1; off < 1024; off <<= 1) {
    int v = (t >= off) ? s[t - off] : 0;
    __syncthreads();
    s[t] += v;
    __syncthreads();
  }
  offsets[t] = s[t] - c;
  out_den[t] = 0.99f * ema_denom[t] + 0.01f * (float)c;
}

__global__ __launch_bounds__(256) void scatter_kernel(
    const int* __restrict__ kstar, const int* __restrict__ rank,
    const int* __restrict__ offsets, int* __restrict__ pos_list,
    int* __restrict__ k_list)
{
  const int p = blockIdx.x * 256 + threadIdx.x;
  const int k = kstar[p];
  const int slot = offsets[k] + rank[p];
  pos_list[slot] = p;
  k_list[slot] = k;
}

__global__ __launch_bounds__(512) void zq_kernel(
    const float* __restrict__ ze_pm, const float* __restrict__ emb,
    const int* __restrict__ kstar, float* __restrict__ out)
{
  const int tid = threadIdx.x;
  const int lane = tid & 63;
  const int w = __builtin_amdgcn_readfirstlane(tid >> 6);
  const int p = blockIdx.x * 64 + lane;
  const int b = p >> 12;
  const int n = p & (N_ - 1);
  const int kst = kstar[p];
  const float* zr = ze_pm + (size_t)p * D_ + w * 16;
  const float* ek = emb + (size_t)kst * D_ + w * 16;
  float* op = out + (size_t)b * D_ * N_ + (size_t)(w * 16) * N_ + n;
  float4 zv[4], ev[4];
  #pragma unroll
  for (int r = 0; r < 4; ++r) {
    zv[r] = *(const float4*)&zr[r * 4];
    ev[r] = *(const float4*)&ek[r * 4];
  }
  #pragma unroll
  for (int r = 0; r < 4; ++r) {
    const float* zc = (const float*)&zv[r];
    const float* ec = (const float*)&ev[r];
    #pragma unroll
    for (int jj = 0; jj < 4; ++jj) {
      float zev = zc[jj];
      op[(size_t)(r * 4 + jj) * N_] = zev + (ec[jj] - zev);  // ref order
    }
  }
}

__global__ __launch_bounds__(128) void gsum_kernel(
    const float* __restrict__ ze_pm, const int* __restrict__ pos_list,
    const int* __restrict__ k_list, float* __restrict__ z_sum)
{
  const int d  = threadIdx.x;
  const int i0 = blockIdx.x * 32;
  int   kprev = -1;
  float acc = 0.f;
  #pragma unroll
  for (int ii = 0; ii < 32; ++ii) {
    int p = pos_list[i0 + ii];
    int k = k_list[i0 + ii];
    if (k != kprev) {
      if (kprev >= 0) atomicAdd(&z_sum[(size_t)kprev * D_ + d], acc);
      acc = 0.f;
      kprev = k;
    }
    acc += ze_pm[(size_t)p * D_ + d];
  }
  if (kprev >= 0) atomicAdd(&z_sum[(size_t)kprev * D_ + d], acc);
}

__global__ __launch_bounds__(256) void finalize_num_kernel(
    const float* __restrict__ ema_numer, const float* __restrict__ z_sum,
    float* __restrict__ out)
{
  const int t = blockIdx.x * 256 + threadIdx.x;
  float* out_num = out + (size_t)B_ * D_ * N_;
  out_num[t] = 0.99f * ema_numer[t] + 0.01f * z_sum[t];
}

extern "C" void kernel_launch(void* const* d_in, const int* in_sizes, int n_in,
                              void* d_out, int out_size, void* d_ws, size_t ws_size,
                              hipStream_t stream)
{
  (void)in_sizes; (void)n_in; (void)out_size; (void)ws_size;
  const float* z         = (const float*)d_in[0];
  const float* W         = (const float*)d_in[1];
  const float* emb       = (const float*)d_in[2];
  const float* ema_numer = (const float*)d_in[3];
  const float* ema_denom = (const float*)d_in[4];
  float* out = (float*)d_out;
  char*  ws  = (char*)d_ws;
  float* z_sum   = (float*)(ws + WS_ZSUM);
  int*   counts  = (int*)(ws + WS_CNT);
  int*   flagcnt = (int*)(ws + WS_FLAGC);
  int*   offsets = (int*)(ws + WS_OFF);
  float* q_sq    = (float*)(ws + WS_QSQ);
  float* q_norm  = (float*)(ws + WS_QNORM);
  int*   kstar   = (int*)(ws + WS_KSTAR);
  int*   rank    = (int*)(ws + WS_RANK);
  int*   plist   = (int*)(ws + WS_PLIST);
  int*   klist   = (int*)(ws + WS_KLIST);
  int*   flist   = (int*)(ws + WS_FLIST);
  float* Wt      = (float*)(ws + WS_WT);
  float* ze_pm   = (float*)(ws + WS_ZPM);
  float* ze_sq   = (float*)(ws + WS_ZESQ);
  float* ze_norm = (float*)(ws + WS_ZEN);
  uint4* ze2f    = (uint4*)(ws + WS_ZE2F);
  uint4* emb2f   = (uint4*)(ws + WS_EMB2F);
  float* val1    = (float*)(ws + WS_VAL1);
  int*   idx1    = (int*)(ws + WS_IDX1);
  float* val2    = (float*)(ws + WS_VAL2);
  float* out_den = out + (size_t)B_ * D_ * N_ + K_ * D_;

  hipMemsetAsync(ws, 0, WS_MEMSET, stream);   // z_sum + counts + flagcnt

  prep_kernel<<<196, 256, 0, stream>>>(W, emb, Wt, q_sq, q_norm, emb2f);
  ze_kernel<<<P_ / 64, 512, 0, stream>>>(z, Wt, ze_pm, ze_sq, ze_norm, ze2f);
  mfma_argmin_kernel<<<1024, 512, 0, stream>>>(ze2f, emb2f, ze_sq, ze_norm,
                                               q_sq, q_norm, val1, idx1, val2);
  resolve_kernel<<<P_ / 256, 256, 0, stream>>>(val1, idx1, val2, kstar,
                                               rank, counts, flist, flagcnt);
  fallback_kernel<<<1024, 256, 0, stream>>>(ze_pm, emb, ze_sq, ze_norm,
                                            q_sq, q_norm, flist, flagcnt,
                                            kstar, rank, counts);
  prefix_kernel<<<1, 1024, 0, stream>>>(counts, ema_denom, offsets, out_den);
  scatter_kernel<<<P_ / 256, 256, 0, stream>>>(kstar, rank, offsets, plist, klist);
  zq_kernel<<<P_ / 64, 512, 0, stream>>>(ze_pm, emb, kstar, out);
  gsum_kernel<<<P_ / 32, 128, 0, stream>>>(ze_pm, plist, klist, z_sum);
  finalize_num_kernel<<<K_ * D_ / 256, 256, 0, stream>>>(ema_numer, z_sum, out);
}